// Round 5
// baseline (177.601 us; speedup 1.0000x reference)
//
#include <hip/hip_runtime.h>
#include <hip/hip_cooperative_groups.h>

namespace cg = cooperative_groups;

#define NEXP  64
#define NTOK  32768
#define TOPK  2
#define NFLAT (NTOK * TOPK)   // 65536
#define DM    1024
#define NBLK  256
#define EPB   (NFLAT / NBLK)  // 256
#define CPBLK 2048            // copy grid

typedef float v4f __attribute__((ext_vector_type(4)));

// Output layout (float32, concatenated):
#define O1 ((size_t)NFLAT * DM)
#define O2 (O1 + NFLAT)
#define O3 (O2 + NFLAT)

// ws layout (ints)
#define WS_DET 0                        // NBLK per-block detect OR slots
#define WS_BC  (WS_DET + NBLK)          // NBLK*NEXP block histograms
#define WS_G   (WS_BC + NBLK * NEXP)    // 16*NEXP group sums
#define WS_DST (WS_G + 16 * NEXP)       // NFLAT destinations

// One cooperative kernel: detect int32/int64 layout, per-block histogram,
// hierarchical block-offset computation, stable-rank scatter of indices.
__global__ void k_prep(const int* __restrict__ routing, int* __restrict__ ws,
                       float* __restrict__ outInv, float* __restrict__ outESI,
                       float* __restrict__ outCounts) {
    cg::grid_group grid = cg::this_grid();
    __shared__ int se[EPB];     // expert id per entry (persists across syncs)
    __shared__ int bo[NEXP];    // this block's expert base offsets
    __shared__ int h[NEXP];
    __shared__ int wsum[4][NEXP];
    __shared__ int flag;
    const int t = threadIdx.x;
    const int b = blockIdx.x;

    // ---- Phase A: OR of odd 32-bit words over words [0, NFLAT) (safe under
    // both layouts). int64 -> hi halves all zero. 256 blocks x 64 int4 each.
    {
        const int4* r4 = (const int4*)routing;
        int acc = 0;
        if (t < 64) { int4 w = r4[b * 64 + t]; acc = w.y | w.w; }
        unsigned long long ball = __ballot(acc != 0);  // wave 0 carries it
        if (t == 0) ws[WS_DET + b] = (ball != 0) ? 1 : 0;
    }
    grid.sync();

    // ---- Phase B: reduce detect slots -> stride; per-block histogram.
    if (t == 0) flag = 0;
    __syncthreads();
    if (ws[WS_DET + t] != 0) atomicOr(&flag, 1);   // t in [0,256) == NBLK slots
    if (t < NEXP) h[t] = 0;
    __syncthreads();
    const int stride = flag ? 1 : 2;               // 1=int32, 2=int64 words
    {
        int i = b * EPB + t;
        int e = routing[(size_t)i * stride];
        se[t] = e;
        atomicAdd(&h[e], 1);
    }
    __syncthreads();
    if (t < NEXP) ws[WS_BC + b * NEXP + t] = h[t];
    grid.sync();

    // ---- Phase C1: 16 blocks compute group sums over 16 hist rows each.
    if (b < 16) {
        int w = t >> 6, e = t & 63;
        int s = 0;
        #pragma unroll
        for (int r = 0; r < 4; ++r)
            s += ws[WS_BC + (b * 16 + w * 4 + r) * NEXP + e];
        wsum[w][e] = s;
        __syncthreads();
        if (w == 0)
            ws[WS_G + b * NEXP + e] = wsum[0][e] + wsum[1][e] + wsum[2][e] + wsum[3][e];
    }
    grid.sync();

    // ---- Phase C2: each block derives its own expert base offsets (wave 0).
    if (t < 64) {
        const int e = t;
        const int g = b >> 4;
        int tot = 0, preg = 0;
        #pragma unroll
        for (int k = 0; k < 16; ++k) {
            int Gk = ws[WS_G + k * NEXP + e];
            tot += Gk;
            if (k < g) preg += Gk;
        }
        int prer = 0;
        for (int bb = g * 16; bb < b; ++bb) prer += ws[WS_BC + bb * NEXP + e];
        // exclusive prefix over experts (wave-wide scan of tot)
        int x = tot;
        #pragma unroll
        for (int d = 1; d < 64; d <<= 1) {
            int y = __shfl_up(x, d, 64);
            if (e >= d) x += y;
        }
        bo[e] = (x - tot) + preg + prer;
        if (b == 0) outCounts[e] = (float)tot;
    }
    __syncthreads();

    // ---- Phase D: stable rank within block + index outputs.
    {
        int e = se[t];
        int rank = 0;
        for (int j = 0; j < t; ++j) rank += (se[j] == e) ? 1 : 0;
        int dst = bo[e] + rank;
        int i = b * EPB + t;
        ws[WS_DST + i] = dst;
        outInv[dst] = (float)i;
        outESI[i] = (float)i;
    }
}

// BW-bound row copy: read each token row once, write its two destinations.
__global__ void k_copy(const float* __restrict__ hidden, const int* __restrict__ ws,
                       float* __restrict__ out) {
    int t = threadIdx.x;
    #pragma unroll 2
    for (int it = 0; it < NTOK / CPBLK; ++it) {
        int tok = it * CPBLK + blockIdx.x;
        const v4f* src = (const v4f*)(hidden + (size_t)tok * DM);
        v4f v = __builtin_nontemporal_load(src + t);
        int d0 = ws[WS_DST + 2 * tok];
        int d1 = ws[WS_DST + 2 * tok + 1];
        __builtin_nontemporal_store(v, (v4f*)(out + (size_t)d0 * DM) + t);
        __builtin_nontemporal_store(v, (v4f*)(out + (size_t)d1 * DM) + t);
    }
}

extern "C" void kernel_launch(void* const* d_in, const int* in_sizes, int n_in,
                              void* d_out, int out_size, void* d_ws, size_t ws_size,
                              hipStream_t stream) {
    const float* hidden = (const float*)d_in[0];
    const int* routing = (const int*)d_in[1];
    float* out = (float*)d_out;
    int* ws = (int*)d_ws;

    float* outInv = out + O1;
    float* outESI = out + O2;
    float* outCounts = out + O3;

    void* args[] = {(void*)&routing, (void*)&ws, (void*)&outInv,
                    (void*)&outESI, (void*)&outCounts};
    hipLaunchCooperativeKernel((const void*)k_prep, dim3(NBLK), dim3(EPB),
                               args, 0, stream);
    k_copy<<<CPBLK, EPB, 0, stream>>>(hidden, ws, out);
}

// Round 6
// 83.276 us; speedup vs baseline: 2.1327x; 2.1327x over previous
//
#include <hip/hip_runtime.h>

#define NEXP  64
#define NTOK  32768
#define TOPK  2
#define NFLAT (NTOK * TOPK)   // 65536
#define DM    1024
#define NBLK  256
#define EPB   (NFLAT / NBLK)  // 256
#define DETBLK 64
#define CPBLK 2048

typedef float v4f __attribute__((ext_vector_type(4)));

// Output layout (float32, concatenated):
#define O1 ((size_t)NFLAT * DM)
#define O2 (O1 + NFLAT)
#define O3 (O2 + NFLAT)

// ws layout (ints)
#define WS_DET    0                      // DETBLK per-block OR slots
#define WS_BC     (WS_DET + DETBLK)      // NBLK*NEXP block counts
#define WS_BO     (WS_BC + NBLK * NEXP)  // NBLK*NEXP block offsets
#define WS_DST    (WS_BO + NBLK * NEXP)  // NFLAT destinations

// Detect int64 vs int32 routing layout. Reads only words [0, NFLAT) (safe
// under both layouts). int64 -> odd words (hi halves of elems 0..32767) all 0.
__global__ void k_detect(const int4* __restrict__ routing4, int* __restrict__ ws) {
    __shared__ int o;
    int t = threadIdx.x;
    if (t == 0) o = 0;
    __syncthreads();
    int k = blockIdx.x * 256 + t;   // 64 blocks * 256 = 16384 int4 = NFLAT words
    int4 w = routing4[k];
    int acc = w.y | w.w;
    if (__any(acc != 0)) { if ((t & 63) == 0) atomicOr(&o, 1); }
    __syncthreads();
    if (t == 0) ws[WS_DET + blockIdx.x] = o;
}

// Reduce the DETBLK detect slots to a stride (1=int32, 2=int64 words).
__device__ __forceinline__ int get_stride(const int* ws) {
    __shared__ int strideSh;
    int t = threadIdx.x;
    if (t < 64) {
        int v = ws[WS_DET + t];
        unsigned long long b = __ballot(v != 0);
        if (t == 0) strideSh = b ? 1 : 2;
    }
    __syncthreads();
    return strideSh;
}

__global__ void k_hist(const int* __restrict__ routing, int* __restrict__ ws) {
    __shared__ int h[NEXP];
    int t = threadIdx.x;
    const int stride = get_stride(ws);
    if (t < NEXP) h[t] = 0;
    __syncthreads();
    int i = blockIdx.x * EPB + t;
    int e = routing[(size_t)i * stride];
    atomicAdd(&h[e], 1);
    __syncthreads();
    if (t < NEXP) ws[WS_BC + blockIdx.x * NEXP + t] = h[t];
}

// 256 threads = 4 waves; wave c owns blocks [c*64,(c+1)*64), lane = expert.
__global__ void k_offsets(int* __restrict__ ws, float* __restrict__ outCounts) {
    __shared__ int partial[4][NEXP];
    __shared__ int chunkbase[4][NEXP];
    __shared__ int startLds[NEXP];
    int t = threadIdx.x;
    int e = t & 63, c = t >> 6;
    int sum = 0;
    #pragma unroll 8
    for (int b = c * 64; b < (c + 1) * 64; ++b) sum += ws[WS_BC + b * NEXP + e];
    partial[c][e] = sum;
    __syncthreads();
    if (c == 0) {
        int p0 = partial[0][e], p1 = partial[1][e], p2 = partial[2][e], p3 = partial[3][e];
        int tot = p0 + p1 + p2 + p3;
        chunkbase[0][e] = 0; chunkbase[1][e] = p0;
        chunkbase[2][e] = p0 + p1; chunkbase[3][e] = p0 + p1 + p2;
        int x = tot;
        for (int d = 1; d < 64; d <<= 1) {
            int y = __shfl_up(x, d, 64);
            if (e >= d) x += y;
        }
        startLds[e] = x - tot;  // exclusive prefix
        outCounts[e] = (float)tot;
    }
    __syncthreads();
    int run = startLds[e] + chunkbase[c][e];
    #pragma unroll 8
    for (int b = c * 64; b < (c + 1) * 64; ++b) {
        ws[WS_BO + b * NEXP + e] = run;
        run += ws[WS_BC + b * NEXP + e];
    }
}

// Stable scatter: dst = blockOffset[b][e] + rank_within_block.
__global__ void k_scatter(const int* __restrict__ routing, int* __restrict__ ws,
                          float* __restrict__ outInv, float* __restrict__ outESI) {
    __shared__ int se[EPB];
    int t = threadIdx.x;
    const int stride = get_stride(ws);
    int i = blockIdx.x * EPB + t;
    int e = routing[(size_t)i * stride];
    se[t] = e;
    __syncthreads();
    int rank = 0;
    for (int j = 0; j < t; ++j) rank += (se[j] == e) ? 1 : 0;
    int dst = ws[WS_BO + blockIdx.x * NEXP + e] + rank;
    ws[WS_DST + i] = dst;
    outInv[dst] = (float)i;
    outESI[i]  = (float)i;
}

// Copy: TEMPORAL loads (hidden is 128 MiB -> LLC-resident across replays),
// nontemporal stores (write-once 256 MiB stream; no RFO, no LLC pollution).
__global__ void k_copy(const float* __restrict__ hidden, const int* __restrict__ ws,
                       float* __restrict__ out) {
    int t = threadIdx.x;
    #pragma unroll 2
    for (int it = 0; it < NTOK / CPBLK; ++it) {
        int tok = it * CPBLK + blockIdx.x;
        const v4f* src = (const v4f*)(hidden + (size_t)tok * DM);
        v4f v = src[t];
        int d0 = ws[WS_DST + 2 * tok];
        int d1 = ws[WS_DST + 2 * tok + 1];
        __builtin_nontemporal_store(v, (v4f*)(out + (size_t)d0 * DM) + t);
        __builtin_nontemporal_store(v, (v4f*)(out + (size_t)d1 * DM) + t);
    }
}

extern "C" void kernel_launch(void* const* d_in, const int* in_sizes, int n_in,
                              void* d_out, int out_size, void* d_ws, size_t ws_size,
                              hipStream_t stream) {
    const float* hidden = (const float*)d_in[0];
    const int* routing = (const int*)d_in[1];
    float* out = (float*)d_out;
    int* ws = (int*)d_ws;

    k_detect<<<DETBLK, 256, 0, stream>>>((const int4*)routing, ws);
    k_hist<<<NBLK, EPB, 0, stream>>>(routing, ws);
    k_offsets<<<1, 256, 0, stream>>>(ws, out + O3);
    k_scatter<<<NBLK, EPB, 0, stream>>>(routing, ws, out + O1, out + O2);
    k_copy<<<CPBLK, EPB, 0, stream>>>(hidden, ws, out);
}

// Round 7
// 76.886 us; speedup vs baseline: 2.3099x; 1.0831x over previous
//
#include <hip/hip_runtime.h>

#define NEXP  64
#define NTOK  32768
#define TOPK  2
#define NFLAT (NTOK * TOPK)   // 65536
#define DM    1024
#define NBLK  256
#define EPB   (NFLAT / NBLK)  // 256
#define DETBLK 64

typedef float v4f __attribute__((ext_vector_type(4)));

// Output layout (float32, concatenated):
#define O1 ((size_t)NFLAT * DM)
#define O2 (O1 + NFLAT)
#define O3 (O2 + NFLAT)

// ws layout (ints)
#define WS_DET 0                      // DETBLK per-block OR slots
#define WS_BC  (WS_DET + DETBLK)      // NBLK*NEXP block histograms

// Detect int64 vs int32 routing layout. Reads only words [0, NFLAT) (safe
// under both layouts). int64 -> odd words (hi halves of elems 0..32767) all 0.
__global__ void k_detect(const int4* __restrict__ routing4, int* __restrict__ ws) {
    __shared__ int o;
    int t = threadIdx.x;
    if (t == 0) o = 0;
    __syncthreads();
    int k = blockIdx.x * 256 + t;   // 64 blocks * 256 = 16384 int4 = NFLAT words
    int4 w = routing4[k];
    int acc = w.y | w.w;
    if (__any(acc != 0)) { if ((t & 63) == 0) atomicOr(&o, 1); }
    __syncthreads();
    if (t == 0) ws[WS_DET + blockIdx.x] = o;
}

__device__ __forceinline__ int get_stride(const int* ws) {
    __shared__ int strideSh;
    int t = threadIdx.x;
    if (t < 64) {
        int v = ws[WS_DET + t];
        unsigned long long b = __ballot(v != 0);
        if (t == 0) strideSh = b ? 1 : 2;
    }
    __syncthreads();
    return strideSh;
}

__global__ void k_hist(const int* __restrict__ routing, int* __restrict__ ws) {
    __shared__ int h[NEXP];
    int t = threadIdx.x;
    const int stride = get_stride(ws);
    if (t < NEXP) h[t] = 0;
    __syncthreads();
    int i = blockIdx.x * EPB + t;
    int e = routing[(size_t)i * stride];
    atomicAdd(&h[e], 1);
    __syncthreads();
    if (t < NEXP) ws[WS_BC + blockIdx.x * NEXP + t] = h[t];
}

// Fused: per-block expert base offsets (from all block-histograms) +
// stable-rank scatter (index outputs) + row copy (dsts local in LDS).
// 256 blocks x 512 threads; block b owns entries [256b,256b+256) =
// tokens [128b, 128b+128).
__global__ void __launch_bounds__(512)
k_main(const int* __restrict__ routing, const int* __restrict__ ws,
       const float* __restrict__ hidden, float* __restrict__ out) {
    __shared__ int se[EPB];
    __shared__ int dstSh[EPB];
    __shared__ int s1h[4][NEXP], s2h[4][NEXP];
    __shared__ int boSh[NEXP];
    const int t = threadIdx.x;
    const int b = blockIdx.x;
    const int stride = get_stride(ws);

    if (t < EPB) {
        int i = b * EPB + t;
        se[t] = routing[(size_t)i * stride];
    }
    // Expert base offsets: wave c sums hist quarter [64c, 64c+64).
    if (t < 256) {
        int e = t & 63, c = t >> 6;
        int s1 = 0, s2 = 0;
        #pragma unroll 8
        for (int r = c * 64; r < c * 64 + 64; ++r) {
            int v = ws[WS_BC + r * NEXP + e];
            s2 += v;
            s1 += (r < b) ? v : 0;
        }
        s1h[c][e] = s1; s2h[c][e] = s2;
    }
    __syncthreads();
    if (t < 64) {
        int e = t;
        int pre = s1h[0][e] + s1h[1][e] + s1h[2][e] + s1h[3][e];
        int tot = s2h[0][e] + s2h[1][e] + s2h[2][e] + s2h[3][e];
        int x = tot;
        #pragma unroll
        for (int d = 1; d < 64; d <<= 1) {
            int y = __shfl_up(x, d, 64);
            if (e >= d) x += y;
        }
        boSh[e] = (x - tot) + pre;          // expert prefix + prior blocks
        if (b == 0) out[O3 + e] = (float)tot;
    }
    __syncthreads();
    // Stable rank within block + index outputs.
    if (t < 256) {
        int e = se[t];
        int rank = 0;
        for (int j = 0; j < t; ++j) rank += (se[j] == e) ? 1 : 0;
        int dst = boSh[e] + rank;
        dstSh[t] = dst;
        int i = b * EPB + t;
        out[O1 + dst] = (float)i;
        out[O2 + i] = (float)i;
    }
    __syncthreads();
    // Copy: 512 threads handle 2 tokens per iteration (1 float4 each).
    const int half = t >> 8;     // which of the 2 tokens
    const int lt = t & 255;      // float4 slot within the row
    #pragma unroll 4
    for (int k = 0; k < 128; k += 2) {
        int tokLocal = k + half;
        int tok = b * 128 + tokLocal;
        const v4f* src = (const v4f*)(hidden + (size_t)tok * DM);
        v4f v = src[lt];
        int d0 = dstSh[2 * tokLocal];
        int d1 = dstSh[2 * tokLocal + 1];
        __builtin_nontemporal_store(v, (v4f*)(out + (size_t)d0 * DM) + lt);
        __builtin_nontemporal_store(v, (v4f*)(out + (size_t)d1 * DM) + lt);
    }
}

extern "C" void kernel_launch(void* const* d_in, const int* in_sizes, int n_in,
                              void* d_out, int out_size, void* d_ws, size_t ws_size,
                              hipStream_t stream) {
    const float* hidden = (const float*)d_in[0];
    const int* routing = (const int*)d_in[1];
    float* out = (float*)d_out;
    int* ws = (int*)d_ws;

    k_detect<<<DETBLK, 256, 0, stream>>>((const int4*)routing, ws);
    k_hist<<<NBLK, EPB, 0, stream>>>(routing, ws);
    k_main<<<NBLK, 512, 0, stream>>>(routing, ws, hidden, out);
}